// Round 4
// baseline (215.140 us; speedup 1.0000x reference)
//
#include <hip/hip_runtime.h>

#define BATCH    8192
#define CTX      32
#define ROUTES   24
#define EDIM     128
#define NSLICE   24
#define WPB      4
#define K2_BLOCKS (BATCH / WPB)

// ---------------- Kernel 1: ctx[b] = sum_c input_embed[context[b,c]] -------
// One thread per (row, 4-dim chunk): 32 fully independent float4 gathers,
// no shuffles, no phase barriers -> maximal MLP, streams near HBM rate.
// Half-wave (32 lanes) covers one full E=128 row, coalesced 512B.
__global__ __launch_bounds__(256) void tale_ctx(
    const int* __restrict__ context,        // (B, C)
    const float* __restrict__ input_embed,  // (NUM_LOC, E)
    float* __restrict__ ctx_out)            // (B, E)  in d_ws
{
    const int gid  = blockIdx.x * 256 + threadIdx.x;
    const int lane = threadIdx.x & 63;
    const int half = lane >> 5;
    const int sub  = lane & 31;             // owns dims 4*sub .. 4*sub+3
    const int b    = gid >> 5;              // 32 threads per row

    // lane sub of each half loads index #sub of its row (coalesced)
    const int cidx = context[b * CTX + sub];

    float4 acc = make_float4(0.f, 0.f, 0.f, 0.f);
    #pragma unroll
    for (int c = 0; c < CTX; ++c) {
        const int idx = __shfl(cidx, (half << 5) + c);
        const float4 v = *reinterpret_cast<const float4*>(
            input_embed + (size_t)idx * EDIM + (sub << 2));
        acc.x += v.x; acc.y += v.y; acc.z += v.z; acc.w += v.w;
    }
    *reinterpret_cast<float4*>(ctx_out + (size_t)b * EDIM + (sub << 2)) = acc;
}

// ---------------- Kernel 2: dots, softmax, route product, loss -------------
// Wave per row; half-wave owns one gather row per dot (32 x float4 = 512B).
// All 12 route gathers issue immediately (addresses independent of ctx);
// slice softmax (L1-hot 12KB table) computes under the gather latency.
__global__ __launch_bounds__(256, 4) void tale_dots(
    const int* __restrict__ route,              // (B, R)
    const int* __restrict__ lr,                 // (B, R)
    const int* __restrict__ slice_idx,          // (B,)
    const float* __restrict__ ctx_in,           // (B, E) from d_ws
    const float* __restrict__ inner_node_embed, // (NUM_INNER+1, E)
    const float* __restrict__ slice_node_embed, // (NSLICE, E)
    float* __restrict__ out)
{
    const int tid  = threadIdx.x;
    const int lane = tid & 63;
    const int half = lane >> 5;
    const int sub  = lane & 31;
    const int w    = tid >> 6;
    const int b    = blockIdx.x * WPB + w;

    __shared__ float bs[WPB];

    int ridx = 0, lridx = 0;
    if (lane < ROUTES) {
        ridx  = route[b * ROUTES + lane];
        lridx = lr[b * ROUTES + lane];
    }
    const int si = slice_idx[b];

    // ctx chunk for this lane (both halves read same 512B row; L1/L2 hot)
    const float4 acc = *reinterpret_cast<const float4*>(
        ctx_in + (size_t)b * EDIM + (sub << 2));

    // ---- issue ALL route gathers up front; addresses need only ridx ----
    int   idxs[12];
    float4 rv[12];
    #pragma unroll
    for (int i = 0; i < 12; ++i) {
        idxs[i] = __shfl(ridx, 2 * i + half);
        rv[i] = *reinterpret_cast<const float4*>(
            inner_node_embed + (size_t)idxs[i] * EDIM + (sub << 2));
    }

    // ---- slice logits + softmax (overlaps with in-flight gathers) ----
    float sd[12], selv = 0.f;
    #pragma unroll
    for (int i = 0; i < 12; ++i) {
        const int d = 2 * i + half;
        const float4 v = *reinterpret_cast<const float4*>(
            slice_node_embed + d * EDIM + (sub << 2));
        float p = v.x * acc.x + v.y * acc.y + v.z * acc.z + v.w * acc.w;
        p += __shfl_xor(p, 16);
        p += __shfl_xor(p, 8);
        p += __shfl_xor(p, 4);
        p += __shfl_xor(p, 2);
        p += __shfl_xor(p, 1);
        sd[i] = p;
        if (d == si) selv = p;
    }
    float m01 = fmaxf(sd[0], sd[1]),  m23 = fmaxf(sd[2], sd[3]);
    float m45 = fmaxf(sd[4], sd[5]),  m67 = fmaxf(sd[6], sd[7]);
    float m89 = fmaxf(sd[8], sd[9]),  mAB = fmaxf(sd[10], sd[11]);
    float mh = fmaxf(fmaxf(fmaxf(m01, m23), fmaxf(m45, m67)), fmaxf(m89, mAB));
    const float M = fmaxf(mh, __shfl_xor(mh, 32));
    float den = 0.f;
    #pragma unroll
    for (int i = 0; i < 12; ++i) den += __expf(sd[i] - M);
    den += __shfl_xor(den, 32);
    const float sel = __shfl(selv, (si & 1) << 5);
    const float slice_pre = __expf(sel - M) / den;

    // ---- route dots + sigmoid product ----
    float prodv = 1.f;
    #pragma unroll
    for (int i = 0; i < 12; ++i) {
        float p = rv[i].x * acc.x + rv[i].y * acc.y
                + rv[i].z * acc.z + rv[i].w * acc.w;
        p += __shfl_xor(p, 16);
        p += __shfl_xor(p, 8);
        p += __shfl_xor(p, 4);
        p += __shfl_xor(p, 2);
        p += __shfl_xor(p, 1);
        const int l = __shfl(lridx, 2 * i + half);
        const float sg = 1.f / (1.f + __expf(-p));
        float h = l ? sg : (1.f - sg);
        if (idxs[i] == 0) h = 1.f;      // padded route position
        prodv *= h;
    }
    prodv *= __shfl_xor(prodv, 32);

    const float pr = slice_pre * prodv;

    if (lane == 0) bs[w] = pr;
    __syncthreads();
    if (tid == 0) {
        const float s = bs[0] + bs[1] + bs[2] + bs[3];
        // out accumulates (1/K2_BLOCKS - blockSum/B) over blocks -> 1 - mean
        atomicAdd(out, 1.0f / K2_BLOCKS - s * (1.0f / BATCH));
    }
}

extern "C" void kernel_launch(void* const* d_in, const int* in_sizes, int n_in,
                              void* d_out, int out_size, void* d_ws, size_t ws_size,
                              hipStream_t stream)
{
    const int*   context          = (const int*)  d_in[0];
    const int*   route            = (const int*)  d_in[1];
    const int*   lr               = (const int*)  d_in[2];
    const int*   slice_idx        = (const int*)  d_in[3];
    const float* input_embed      = (const float*)d_in[4];
    const float* inner_node_embed = (const float*)d_in[5];
    const float* slice_node_embed = (const float*)d_in[6];
    float* out = (float*)d_out;
    float* ctx = (float*)d_ws;                 // (B, E) fp32 = 4 MB scratch

    hipMemsetAsync(out, 0, sizeof(float), stream);

    tale_ctx<<<BATCH * 32 / 256, 256, 0, stream>>>(context, input_embed, ctx);

    tale_dots<<<K2_BLOCKS, 64 * WPB, 0, stream>>>(
        route, lr, slice_idx, ctx, inner_node_embed, slice_node_embed, out);
}

// Round 5
// 208.090 us; speedup vs baseline: 1.0339x; 1.0339x over previous
//
#include <hip/hip_runtime.h>

#define BATCH    8192
#define CTX      32
#define ROUTES   24
#define EDIM     128
#define NSLICE   24
#define WPB      4
#define NBLOCKS  (BATCH / WPB)

typedef float f4 __attribute__((ext_vector_type(4)));

// One wave per batch row. Lanes split into two 32-lane halves; each half owns
// one full E=128 row per float4 load (32 x 16B = 512B coalesced). Dot
// reductions are 5-step butterflies within a half (each tree reduces TWO
// dots, one per half). Gather tables (input_embed, inner_node_embed) are
// loaded NONTEMPORAL: random indices over 51/102 MB have ~zero L1 reuse, so
// skipping L1 allocation frees tag/MSHR resources on the miss path.
__global__ __launch_bounds__(256, 8) void tale_fused(
    const int* __restrict__ context,            // (B, C)
    const int* __restrict__ route,              // (B, R)
    const int* __restrict__ lr,                 // (B, R)
    const int* __restrict__ slice_idx,          // (B,)
    const float* __restrict__ input_embed,      // (NUM_LOC, E)
    const float* __restrict__ inner_node_embed, // (NUM_INNER+1, E)
    const float* __restrict__ slice_node_embed, // (NSLICE, E)
    float* __restrict__ out)
{
    const int tid  = threadIdx.x;
    const int lane = tid & 63;
    const int half = lane >> 5;        // 0 = lower half, 1 = upper half
    const int sub  = lane & 31;        // owns dims 4*sub .. 4*sub+3
    const int w    = tid >> 6;
    const int b    = blockIdx.x * WPB + w;

    __shared__ float bs[WPB];

    // ---- per-row indices (one per lane, broadcast via shuffle) ----
    int cidx = 0, ridx = 0, lridx = 0;
    if (lane < CTX) cidx = context[b * CTX + lane];
    if (lane < ROUTES) {
        ridx  = route[b * ROUTES + lane];
        lridx = lr[b * ROUTES + lane];
    }
    const int si = slice_idx[b];

    // ---- context embedding sum ----
    // iteration i: lower half loads context entry i, upper half entry i+16
    f4 acc = (f4)(0.f);
    #pragma unroll
    for (int i = 0; i < 16; ++i) {
        const int idx = __shfl(cidx, i + (half << 4));
        const f4 v = __builtin_nontemporal_load(
            reinterpret_cast<const f4*>(
                input_embed + (size_t)idx * EDIM + (sub << 2)));
        acc += v;
    }
    acc.x += __shfl_xor(acc.x, 32);
    acc.y += __shfl_xor(acc.y, 32);
    acc.z += __shfl_xor(acc.z, 32);
    acc.w += __shfl_xor(acc.w, 32);
    // lane now holds ctx[4*sub .. 4*sub+3]

    // ---- route products: 12 iterations, dots (2i, 2i+1) in the two halves --
    float prodv = 1.f;
    #pragma unroll
    for (int i = 0; i < 12; ++i) {
        const int d   = 2 * i + half;
        const int idx = __shfl(ridx, d);
        const int l   = __shfl(lridx, d);
        const f4 v = __builtin_nontemporal_load(
            reinterpret_cast<const f4*>(
                inner_node_embed + (size_t)idx * EDIM + (sub << 2)));
        float p = v.x * acc.x + v.y * acc.y + v.z * acc.z + v.w * acc.w;
        p += __shfl_xor(p, 16);
        p += __shfl_xor(p, 8);
        p += __shfl_xor(p, 4);
        p += __shfl_xor(p, 2);
        p += __shfl_xor(p, 1);          // full dot, uniform within half
        const float sg = 1.f / (1.f + __expf(-p));
        float h = l ? sg : (1.f - sg);
        if (idx == 0) h = 1.f;          // padded route position
        prodv *= h;
    }
    prodv *= __shfl_xor(prodv, 32);     // even-half * odd-half products

    // ---- slice softmax: two independent online chains (even/odd slices) ----
    float m = -3.0e38f, den = 0.f, selv = 0.f;
    #pragma unroll
    for (int i = 0; i < 12; ++i) {
        const int s = 2 * i + half;
        const float4 v = *reinterpret_cast<const float4*>(
            slice_node_embed + s * EDIM + (sub << 2));
        float p = v.x * acc.x + v.y * acc.y + v.z * acc.z + v.w * acc.w;
        p += __shfl_xor(p, 16);
        p += __shfl_xor(p, 8);
        p += __shfl_xor(p, 4);
        p += __shfl_xor(p, 2);
        p += __shfl_xor(p, 1);
        const float mN = fmaxf(m, p);
        den = den * __expf(m - mN) + __expf(p - mN);
        m = mN;
        if (s == si) selv = p;
    }
    const float m_o   = __shfl_xor(m, 32);
    const float den_o = __shfl_xor(den, 32);
    const float M     = fmaxf(m, m_o);
    const float dtot  = den * __expf(m - M) + den_o * __expf(m_o - M);
    const float sel   = __shfl(selv, (si & 1) << 5);
    const float slice_pre = __expf(sel - M) / dtot;

    const float pr = slice_pre * prodv;

    if (lane == 0) bs[w] = pr;
    __syncthreads();
    if (tid == 0) {
        const float s = bs[0] + bs[1] + bs[2] + bs[3];
        // out accumulates (1/NBLOCKS - blockSum/B) over blocks -> 1 - mean
        atomicAdd(out, 1.0f / NBLOCKS - s * (1.0f / BATCH));
    }
}

extern "C" void kernel_launch(void* const* d_in, const int* in_sizes, int n_in,
                              void* d_out, int out_size, void* d_ws, size_t ws_size,
                              hipStream_t stream)
{
    const int*   context          = (const int*)  d_in[0];
    const int*   route            = (const int*)  d_in[1];
    const int*   lr               = (const int*)  d_in[2];
    const int*   slice_idx        = (const int*)  d_in[3];
    const float* input_embed      = (const float*)d_in[4];
    const float* inner_node_embed = (const float*)d_in[5];
    const float* slice_node_embed = (const float*)d_in[6];
    float* out = (float*)d_out;

    // d_out is poisoned 0xAA before every launch; zero it, then blocks
    // atomic-accumulate so the final value is 1 - mean.
    hipMemsetAsync(out, 0, sizeof(float), stream);

    tale_fused<<<NBLOCKS, 64 * WPB, 0, stream>>>(
        context, route, lr, slice_idx,
        input_embed, inner_node_embed, slice_node_embed, out);
}